// Round 3
// baseline (255.044 us; speedup 1.0000x reference)
//
#include <hip/hip_runtime.h>
#include <hip/hip_bf16.h>
#include <math.h>

typedef __hip_bfloat16 bf16;
typedef __attribute__((ext_vector_type(8))) short bf16x8;
typedef __attribute__((ext_vector_type(4))) float f32x4;
typedef __attribute__((ext_vector_type(8))) int i32x8;
typedef __attribute__((ext_vector_type(4))) int i32x4;
typedef unsigned char u8;
typedef unsigned int u32;

#define T_SEQ   256
#define C_EMB   384
#define NH      6
#define HS      4
#define NB      128
#define NTOK    (NB * T_SEQ)   // 32768
#define VOC     65
#define FFDIM   1536
#define QKVW    72
#define PROJK   32
#define XROWS   (VOC * T_SEQ)  // 16640

#define X2_SCALE    128.0f
#define W1_SCALE    128.0f
#define FF1_DESCALE (1.0f / (128.0f * 128.0f))
#define H1_SCALE    512.0f
#define W2_SCALE    128.0f
#define FF2_DESCALE (1.0f / (512.0f * 128.0f))

__device__ __forceinline__ float bf2f(bf16 x) { return __bfloat162float(x); }
__device__ __forceinline__ bf16  f2b(float x) { return __float2bfloat16(x); }
__device__ __forceinline__ short f2s(float x) { bf16 b = __float2bfloat16(x); return *reinterpret_cast<short*>(&b); }
__device__ __forceinline__ u8 f2fp8(float x) {
    return (u8)(__builtin_amdgcn_cvt_pk_fp8_f32(x, x, 0, false) & 0xff);
}
__device__ __forceinline__ u32 pk4fp8(const float* w) {
    int p = __builtin_amdgcn_cvt_pk_fp8_f32(w[0], w[1], 0, false);
    p = __builtin_amdgcn_cvt_pk_fp8_f32(w[2], w[3], p, true);
    return (u32)p;
}

// async 16B global->LDS. LDS dst = wave-uniform base + lane*16; global addr per-lane (gather ok).
__device__ __forceinline__ void glds16(const void* g, void* l) {
    __builtin_amdgcn_global_load_lds((const __attribute__((address_space(1))) void*)g,
                                     (__attribute__((address_space(3))) void*)l, 16, 0, 0);
}

// ---------------- all weight packing + embedding table + loss-accumulator init, ONE dispatch
__global__ void pack_all_kernel(const float* __restrict__ Wq, const float* __restrict__ Wk,
                                const float* __restrict__ Wv, const float* __restrict__ Wlm,
                                const float* __restrict__ Wproj,
                                const float* __restrict__ W1, const float* __restrict__ W2,
                                const float* __restrict__ tok_emb, const float* __restrict__ pos_emb,
                                bf16* __restrict__ WqkvT, bf16* __restrict__ WlmT,
                                bf16* __restrict__ WprojT, u8* __restrict__ W1f8,
                                u8* __restrict__ W2f8, bf16* __restrict__ xtab,
                                float* __restrict__ lossbuf) {
    int blk = blockIdx.x;
    if (blk == 0 && threadIdx.x == 0) { lossbuf[0] = 0.f; ((int*)lossbuf)[1] = 0; }
    if (blk < 128) {                                   // WqkvT [128,384]
        int n = blk;
        for (int c = threadIdx.x; c < C_EMB; c += 256) {
            float v = 0.f;
            if (n < QKVW) {
                int sel = n / 24, r = n % 24, h = r >> 2, d = r & 3;
                const float* W = (sel == 0) ? Wq : (sel == 1) ? Wk : Wv;
                v = W[(h * C_EMB + c) * HS + d];
            }
            WqkvT[(size_t)n * C_EMB + c] = f2b(v);
        }
    } else if (blk < 256) {                            // WlmT [128,384]
        int n = blk - 128;
        for (int c = threadIdx.x; c < C_EMB; c += 256)
            WlmT[(size_t)n * C_EMB + c] = f2b(n < VOC ? Wlm[(size_t)c * VOC + n] : 0.f);
    } else if (blk < 640) {                            // WprojT [384,32]
        int n = blk - 256;
        int k = threadIdx.x;
        if (k < PROJK)
            WprojT[(size_t)n * PROJK + k] = f2b(k < 24 ? Wproj[(size_t)k * C_EMB + n] : 0.f);
    } else if (blk < 640 + FFDIM) {                    // W1f8 [1536,384] fp8 * W1_SCALE
        int n = blk - 640;
        for (int k = threadIdx.x; k < C_EMB; k += 256)
            W1f8[(size_t)n * C_EMB + k] = f2fp8(W1[(size_t)k * FFDIM + n] * W1_SCALE);
    } else if (blk < 640 + FFDIM + C_EMB) {            // W2f8 [384,1536] fp8 * W2_SCALE
        int n = blk - 640 - FFDIM;
        for (int k = threadIdx.x; k < FFDIM; k += 256)
            W2f8[(size_t)n * FFDIM + k] = f2fp8(W2[(size_t)k * C_EMB + n] * W2_SCALE);
    } else {                                           // xtab [65*256, 384] bf16
        int base = (blk - (640 + FFDIM + C_EMB)) * 4;
        for (int r = 0; r < 4; ++r) {
            int row = base + r;
            int id = row >> 8, t = row & 255;
            const float* te = tok_emb + (size_t)id * C_EMB;
            const float* pe = pos_emb + (size_t)t * C_EMB;
            bf16* dst = xtab + (size_t)row * C_EMB;
            for (int c = threadIdx.x; c < C_EMB; c += 256)
                dst[c] = f2b(te[c] + pe[c]);
        }
    }
}

// ---------------- QKV gather-GEMM, 512 threads / 8 waves, BK=64 (128B rows, (r&7)*16 rotation)
__global__ __launch_bounds__(512)
void qkv_gather_kernel(const int* __restrict__ idx, const bf16* __restrict__ xtab,
                       const bf16* __restrict__ Bt, float* __restrict__ outf) {
    __shared__ __align__(16) u8 As[16384];   // [128 rows][128B = 64 bf16], row r rotated by (r&7)*16B
    __shared__ __align__(16) u8 Bs[16384];
    __shared__ int rowid[128];
    int tid = threadIdx.x, lane = tid & 63, wave = tid >> 6;
    int bm = blockIdx.x * 128;
    int wm = (wave & 1) * 64, wn = (wave >> 1) * 32;
    int lrow = lane & 15, kq = lane >> 4;
    if (tid < 128) { int token = bm + tid; rowid[tid] = idx[token] * T_SEQ + (token & (T_SEQ - 1)); }
    __syncthreads();

    int r0 = tid >> 3;
    int s0 = (((tid & 7) * 16) - (r0 & 7) * 16) & 127;
    int c1 = tid + 512;
    int r1 = c1 >> 3;
    int s1 = (((c1 & 7) * 16) - (r1 & 7) * 16) & 127;
    const u8* xb = (const u8*)xtab;
    const u8* bb = (const u8*)Bt;
    long gA0 = (long)rowid[r0] * 768 + s0;
    long gA1 = (long)rowid[r1] * 768 + s1;
    long gB0 = (long)r0 * 768 + s0;
    long gB1 = (long)r1 * 768 + s1;
    int ro = (lrow & 7) * 16;

    f32x4 acc[4][2] = {};
    for (int k0 = 0; k0 < 768; k0 += 128) {            // k0 = byte offset within 768B row
        glds16(xb + gA0 + k0, As + (size_t)tid * 16);
        glds16(xb + gA1 + k0, As + (size_t)c1 * 16);
        glds16(bb + gB0 + k0, Bs + (size_t)tid * 16);
        glds16(bb + gB1 + k0, Bs + (size_t)c1 * 16);
        __syncthreads();
        #pragma unroll
        for (int ks = 0; ks < 2; ++ks) {
            int off = (ks * 64 + kq * 16 + ro) & 127;
            bf16x8 af[4], bff[2];
            #pragma unroll
            for (int i = 0; i < 4; ++i)
                af[i] = *(const bf16x8*)&As[(size_t)(wm + i * 16 + lrow) * 128 + off];
            #pragma unroll
            for (int i = 0; i < 2; ++i)
                bff[i] = *(const bf16x8*)&Bs[(size_t)(wn + i * 16 + lrow) * 128 + off];
            #pragma unroll
            for (int mi = 0; mi < 4; ++mi)
                #pragma unroll
                for (int ni = 0; ni < 2; ++ni)
                    acc[mi][ni] = __builtin_amdgcn_mfma_f32_16x16x32_bf16(af[mi], bff[ni], acc[mi][ni], 0, 0, 0);
        }
        __syncthreads();
    }

    #pragma unroll
    for (int ni = 0; ni < 2; ++ni) {
        int col = wn + ni * 16 + lrow;
        if (col >= QKVW) continue;
        #pragma unroll
        for (int mi = 0; mi < 4; ++mi) {
            int orow = bm + wm + mi * 16 + kq * 4;
            #pragma unroll
            for (int r = 0; r < 4; ++r)
                outf[(size_t)(orow + r) * QKVW + col] = acc[mi][ni][r];
        }
    }
}

// ---------------- causal softmax attention (no-max-stabilization form; scores << 1)
__global__ void attn_kernel(const float* __restrict__ qkv,
                            bf16* __restrict__ attnT) {
    int bh = blockIdx.x;
    int b = bh / NH, h = bh % NH;
    int t = threadIdx.x;
    __shared__ float4 kv[T_SEQ][2];    // [s][0]=k4, [s][1]=v4
    const float* base = qkv + (size_t)(b * T_SEQ) * QKVW;
    kv[t][0] = *(const float4*)(base + t * QKVW + 24 + h * HS);
    kv[t][1] = *(const float4*)(base + t * QKVW + 48 + h * HS);
    __syncthreads();
    const float scale = 0.05103103630798288f;   // 384^-0.5
    float4 q = *(const float4*)(base + t * QKVW + h * HS);
    float qx = q.x * scale, qy = q.y * scale, qz = q.z * scale, qw = q.w * scale;
    float sum0 = 0.f, sum1 = 0.f;
    float o0x = 0.f, o0y = 0.f, o0z = 0.f, o0w = 0.f;
    float o1x = 0.f, o1y = 0.f, o1z = 0.f, o1w = 0.f;
    int s = 0;
    for (; s + 1 <= t; s += 2) {
        float4 k0 = kv[s][0],     v0 = kv[s][1];
        float4 k1 = kv[s + 1][0], v1 = kv[s + 1][1];
        float p0 = __expf(qx * k0.x + qy * k0.y + qz * k0.z + qw * k0.w);
        float p1 = __expf(qx * k1.x + qy * k1.y + qz * k1.z + qw * k1.w);
        sum0 += p0; sum1 += p1;
        o0x += p0 * v0.x; o0y += p0 * v0.y; o0z += p0 * v0.z; o0w += p0 * v0.w;
        o1x += p1 * v1.x; o1y += p1 * v1.y; o1z += p1 * v1.z; o1w += p1 * v1.w;
    }
    if (s <= t) {
        float4 k0 = kv[s][0], v0 = kv[s][1];
        float p0 = __expf(qx * k0.x + qy * k0.y + qz * k0.z + qw * k0.w);
        sum0 += p0;
        o0x += p0 * v0.x; o0y += p0 * v0.y; o0z += p0 * v0.z; o0w += p0 * v0.w;
    }
    float inv = 1.f / (sum0 + sum1);
    bf16* out = attnT + (size_t)(b * T_SEQ + t) * PROJK + h * HS;
    out[0] = f2b((o0x + o1x) * inv);
    out[1] = f2b((o0y + o1y) * inv);
    out[2] = f2b((o0z + o1z) * inv);
    out[3] = f2b((o0w + o1w) * inv);
    if (h == 0) {
        bf16* pad = attnT + (size_t)(b * T_SEQ + t) * PROJK + 24;
        *(uint4*)pad = uint4{0, 0, 0, 0};
    }
}

// ---------------- MEGA v2: proj + FF1 + FF2 fused, 64-token strip per block, 64KB LDS,
// 2 blocks/CU co-residency (the latency-hiding mechanism). W2 fragments stream
// global->register (L2-resident), x2/h1 never touch HBM. Wave split 2M x 4N everywhere.
__global__ __launch_bounds__(512, 4)
void ff_mega_kernel(const bf16* __restrict__ attnT, const bf16* __restrict__ WprojT,
                    const float* __restrict__ bproj,
                    const u8* __restrict__ W1f8, const float* __restrict__ b1,
                    const u8* __restrict__ W2f8, const float* __restrict__ b2,
                    bf16* __restrict__ x3) {
    __shared__ __align__(16) u8 smem[65536];           // 64 KB -> 2 blocks/CU
    u8* x2_lds = smem;                                 // [3][64][128] fp8, (m&7)*16 rotation
    u8* bs1    = smem + 24576;                         // 2 x 16KB W1 k-chunk dbuf
    u8* h1t    = smem + 57344;                         // [64][128] fp8 rotated
    short* As_p = (short*)(smem + 24576);              // proj attn tile [64][32]sh (alias bs1)
    short* Bs_p = (short*)(smem + 28672);              // proj Wproj tile [384][32]sh (alias bs1)

    int tid  = threadIdx.x;
    int lane = tid & 63;
    int wave = tid >> 6;
    int bm   = blockIdx.x * 64;
    int lrow  = lane & 15;
    int khalf = lane >> 4;
    int wmh = (wave & 1) * 32;                         // M half: 2 x 32 rows
    int wn4 = (wave >> 1) * 96;                        // 384-wide N quarter (proj, FF2)
    int wn1 = (wave >> 1) * 32;                        // 128-wide N quarter (FF1)

    // ---- proj staging: A [64][32]sh (tid<256), B [384][32]sh
    if (tid < 256) {
        int row = tid >> 2;
        int i0 = (tid & 3) * 16;
        int selem = ((i0 - ((row >> 1) & 3) * 16) & 63) >> 1;
        glds16(attnT + (size_t)(bm + row) * PROJK + selem, As_p + (size_t)tid * 8);
    }
    #pragma unroll
    for (int p = 0; p < 3; ++p) {
        int c = tid + p * 512;
        int rowb = c >> 2;
        int sel2 = (((c & 3) * 16 - ((rowb >> 1) & 3) * 16) & 63) >> 1;
        glds16(WprojT + (size_t)rowb * PROJK + sel2, Bs_p + (size_t)c * 8);
    }
    __syncthreads();

    // ---- proj compute (K=32, one MFMA step), swapped operands
    f32x4 accp[2][6] = {};
    {
        int arot16 = ((lrow >> 1) & 3) * 16;
        int roff = ((khalf * 16 + arot16) & 63) >> 1;
        bf16x8 afp[2], bfp[6];
        #pragma unroll
        for (int i = 0; i < 2; ++i)
            afp[i] = *(const bf16x8*)&As_p[(size_t)(wmh + i * 16 + lrow) * 32 + roff];
        #pragma unroll
        for (int i = 0; i < 6; ++i)
            bfp[i] = *(const bf16x8*)&Bs_p[(size_t)(wn4 + i * 16 + lrow) * 32 + roff];
        #pragma unroll
        for (int mi = 0; mi < 2; ++mi)
            #pragma unroll
            for (int ni = 0; ni < 6; ++ni)
                accp[mi][ni] = __builtin_amdgcn_mfma_f32_16x16x32_bf16(bfp[ni], afp[mi], accp[mi][ni], 0, 0, 0);
    }
    __syncthreads();                                   // all proj LDS reads done (bs1 alias safe)

    // staging address math (fp8 128B rows, (r&7)*16 rotation)
    int r0 = tid >> 3;
    int s0 = (((tid & 7) * 16) - (r0 & 7) * 16) & 127;

    // issue W1 chunk 0 (flies under the proj epilogue)
    {
        const u8* g = W1f8 + (size_t)r0 * 384 + s0;
        glds16(g, bs1 + (size_t)tid * 16);
        glds16(g + (size_t)64 * 384, bs1 + 8192 + (size_t)tid * 16);
    }

    // proj epilogue -> x2_lds (fp8 * X2_SCALE, rotated)
    #pragma unroll
    for (int mi = 0; mi < 2; ++mi) {
        int m = wmh + mi * 16 + lrow;
        #pragma unroll
        for (int ni = 0; ni < 6; ++ni) {
            int n0 = wn4 + ni * 16 + khalf * 4;
            float4 bv = *(const float4*)(bproj + n0);
            float w[4];
            w[0] = (accp[mi][ni][0] + bv.x) * X2_SCALE;
            w[1] = (accp[mi][ni][1] + bv.y) * X2_SCALE;
            w[2] = (accp[mi][ni][2] + bv.z) * X2_SCALE;
            w[3] = (accp[mi][ni][3] + bv.w) * X2_SCALE;
            *(u32*)&x2_lds[(size_t)(n0 >> 7) * 8192 + (size_t)m * 128 +
                           (((n0 & 127) + (m & 7) * 16) & 127)] = pk4fp8(w);
        }
    }
    __syncthreads();                                   // x2 ready, bs1 buf0 ready

    int arot8 = (lrow & 7) * 16;
    int off0 = (khalf * 32 + arot8) & 127;
    int off1 = (off0 + 16) & 127;

    f32x4 acc1[2][2] = {};
    f32x4 acc2[2][6] = {};

    for (int nt = 0; nt < 12; ++nt) {
        // ---- FF1: 3 K-steps over x2 (K=384), W1 dbuf with prefetch
        #pragma unroll
        for (int kk = 0; kk < 3; ++kk) {
            int stp = nt * 3 + kk;
            if (stp + 1 < 36) {                        // prefetch next W1 k-chunk
                int nnt = (stp + 1) / 3, nk0 = ((stp + 1) % 3) * 128;
                const u8* g = W1f8 + (size_t)(nnt * 128 + r0) * 384 + nk0 + s0;
                u8* dst = bs1 + (size_t)((stp + 1) & 1) * 16384;
                glds16(g, dst + (size_t)tid * 16);
                glds16(g + (size_t)64 * 384, dst + 8192 + (size_t)tid * 16);
            }
            const u8* abase = x2_lds + (size_t)kk * 8192;
            const u8* bbase = bs1 + (size_t)(stp & 1) * 16384;
            i32x8 a[2], b[2];
            #pragma unroll
            for (int i = 0; i < 2; ++i) {
                const u8* rp = abase + (size_t)(wmh + i * 16 + lrow) * 128;
                i32x4 lo = *(const i32x4*)(rp + off0);
                i32x4 hi = *(const i32x4*)(rp + off1);
                a[i][0]=lo[0]; a[i][1]=lo[1]; a[i][2]=lo[2]; a[i][3]=lo[3];
                a[i][4]=hi[0]; a[i][5]=hi[1]; a[i][6]=hi[2]; a[i][7]=hi[3];
            }
            #pragma unroll
            for (int i = 0; i < 2; ++i) {
                const u8* rp = bbase + (size_t)(wn1 + i * 16 + lrow) * 128;
                i32x4 lo = *(const i32x4*)(rp + off0);
                i32x4 hi = *(const i32x4*)(rp + off1);
                b[i][0]=lo[0]; b[i][1]=lo[1]; b[i][2]=lo[2]; b[i][3]=lo[3];
                b[i][4]=hi[0]; b[i][5]=hi[1]; b[i][6]=hi[2]; b[i][7]=hi[3];
            }
            #pragma unroll
            for (int mi = 0; mi < 2; ++mi)
                #pragma unroll
                for (int ni = 0; ni < 2; ++ni)
                    acc1[mi][ni] = __builtin_amdgcn_mfma_scale_f32_16x16x128_f8f6f4(
                        b[ni], a[mi], acc1[mi][ni], 0, 0,
                        0, 0x7f7f7f7f, 0, 0x7f7f7f7f);
            __syncthreads();
        }

        // ---- h1 epilogue -> h1t (fp8 * H1_SCALE, relu, rotated); zero acc1
        #pragma unroll
        for (int mi = 0; mi < 2; ++mi) {
            int m = wmh + mi * 16 + lrow;
            #pragma unroll
            for (int ni = 0; ni < 2; ++ni) {
                int n0 = wn1 + ni * 16 + khalf * 4;
                float4 bv = *(const float4*)(b1 + nt * 128 + n0);
                float w[4];
                w[0] = fmaxf(acc1[mi][ni][0] * FF1_DESCALE + bv.x, 0.f) * H1_SCALE;
                w[1] = fmaxf(acc1[mi][ni][1] * FF1_DESCALE + bv.y, 0.f) * H1_SCALE;
                w[2] = fmaxf(acc1[mi][ni][2] * FF1_DESCALE + bv.z, 0.f) * H1_SCALE;
                w[3] = fmaxf(acc1[mi][ni][3] * FF1_DESCALE + bv.w, 0.f) * H1_SCALE;
                *(u32*)&h1t[(size_t)m * 128 + ((n0 + (m & 7) * 16) & 127)] = pk4fp8(w);
                acc1[mi][ni] = f32x4{0.f, 0.f, 0.f, 0.f};
            }
        }
        __syncthreads();                               // h1t ready

        // ---- FF2 partial: acc2 += h1t @ W2[k-slice nt]; W2 frags global->reg (L2-resident)
        {
            i32x8 a2[2];
            #pragma unroll
            for (int i = 0; i < 2; ++i) {
                const u8* rp = h1t + (size_t)(wmh + i * 16 + lrow) * 128;
                i32x4 lo = *(const i32x4*)(rp + off0);
                i32x4 hi = *(const i32x4*)(rp + off1);
                a2[i][0]=lo[0]; a2[i][1]=lo[1]; a2[i][2]=lo[2]; a2[i][3]=lo[3];
                a2[i][4]=hi[0]; a2[i][5]=hi[1]; a2[i][6]=hi[2]; a2[i][7]=hi[3];
            }
            #pragma unroll
            for (int half = 0; half < 2; ++half) {
                i32x8 bw[3];
                #pragma unroll
                for (int j = 0; j < 3; ++j) {
                    int n = wn4 + (half * 3 + j) * 16 + lrow;
                    const u8* p = W2f8 + (size_t)n * 1536 + nt * 128 + khalf * 32;
                    i32x4 lo = *(const i32x4*)p;
                    i32x4 hi = *(const i32x4*)(p + 16);
                    bw[j][0]=lo[0]; bw[j][1]=lo[1]; bw[j][2]=lo[2]; bw[j][3]=lo[3];
                    bw[j][4]=hi[0]; bw[j][5]=hi[1]; bw[j][6]=hi[2]; bw[j][7]=hi[3];
                }
                #pragma unroll
                for (int mi = 0; mi < 2; ++mi)
                    #pragma unroll
                    for (int j = 0; j < 3; ++j)
                        acc2[mi][half * 3 + j] = __builtin_amdgcn_mfma_scale_f32_16x16x128_f8f6f4(
                            bw[j], a2[mi], acc2[mi][half * 3 + j], 0, 0,
                            0, 0x7f7f7f7f, 0, 0x7f7f7f7f);
            }
        }
        __syncthreads();                               // h1t free for next nt
    }

    // ---- x3 epilogue: bf16 via rotated LDS [64 rows][3 chunks][256B], coalesced stores
    u8* Ep = smem;                                     // 48KB overlay (x2/bs1/h1t all dead)
    #pragma unroll
    for (int mi = 0; mi < 2; ++mi) {
        int m = wmh + mi * 16 + lrow;
        #pragma unroll
        for (int ni = 0; ni < 6; ++ni) {
            int n0 = wn4 + ni * 16 + khalf * 4;
            float4 bv = *(const float4*)(b2 + n0);
            union { short s[4]; uint2 u; } pk;
            pk.s[0] = f2s(acc2[mi][ni][0] * FF2_DESCALE + bv.x);
            pk.s[1] = f2s(acc2[mi][ni][1] * FF2_DESCALE + bv.y);
            pk.s[2] = f2s(acc2[mi][ni][2] * FF2_DESCALE + bv.z);
            pk.s[3] = f2s(acc2[mi][ni][3] * FF2_DESCALE + bv.w);
            *(uint2*)&Ep[(size_t)m * 768 + ((n0 >> 7) << 8) +
                         ((((n0 & 127) * 2) + (m & 7) * 16) & 255)] = pk.u;
        }
    }
    __syncthreads();
    #pragma unroll
    for (int p = 0; p < 6; ++p) {
        int c = tid + p * 512;
        int row = c / 48;
        int sl = c - row * 48;
        int g0 = sl * 16;
        int chunk = g0 >> 8;
        int loc = g0 & 255;
        uint4 v = *(const uint4*)&Ep[(size_t)row * 768 + (chunk << 8) +
                                     ((loc + (row & 7) * 16) & 255)];
        *(uint4*)((u8*)x3 + (size_t)(bm + row) * 768 + g0) = v;
    }
}

// ---------------- LM head + fused CE loss + grid-level loss finish (atomics)
__global__ __launch_bounds__(512)
void lm_loss_kernel(const bf16* __restrict__ A, const bf16* __restrict__ Bt,
                    const float* __restrict__ bias, const int* __restrict__ targets,
                    float* __restrict__ outf, float* __restrict__ lossbuf,
                    float* __restrict__ out_loss, int M, int K) {
    __shared__ short As[128][32];
    __shared__ short Bs[128][32];
    __shared__ float Ls[128][66];
    __shared__ float red[128];
    int tid  = threadIdx.x;
    int lane = tid & 63;
    int wave = tid >> 6;
    int bm = blockIdx.x * 128;
    int wm = (wave & 1) * 64;
    int wn = (wave >> 1) * 32;
    int lrow  = lane & 15;
    int khalf = lane >> 4;

    int row = tid >> 2;
    int i0 = (tid & 3) * 16;
    int selem = ((i0 - ((row >> 1) & 3) * 16) & 63) >> 1;
    int arot = ((lrow >> 1) & 3) * 16;
    int roff = ((khalf * 16 + arot) & 63) >> 1;

    f32x4 acc[4][2] = {};
    for (int k0 = 0; k0 < K; k0 += 32) {
        glds16(A  + (size_t)(bm + row) * K + k0 + selem, (short*)As + (size_t)tid * 8);
        glds16(Bt + (size_t)row * K + k0 + selem,        (short*)Bs + (size_t)tid * 8);
        __syncthreads();

        bf16x8 af[4], bff[2];
        #pragma unroll
        for (int i = 0; i < 4; ++i)
            af[i] = *(const bf16x8*)&As[wm + i * 16 + lrow][roff];
        #pragma unroll
        for (int i = 0; i < 2; ++i)
            bff[i] = *(const bf16x8*)&Bs[wn + i * 16 + lrow][roff];
        #pragma unroll
        for (int mi = 0; mi < 4; ++mi)
            #pragma unroll
            for (int ni = 0; ni < 2; ++ni)
                acc[mi][ni] = __builtin_amdgcn_mfma_f32_16x16x32_bf16(af[mi], bff[ni], acc[mi][ni], 0, 0, 0);
        __syncthreads();
    }

    #pragma unroll
    for (int ni = 0; ni < 2; ++ni) {
        int col = wn + ni * 16 + lrow;
        if (col >= VOC) continue;
        float bv = bias[col];
        #pragma unroll
        for (int mi = 0; mi < 4; ++mi) {
            int lr = wm + mi * 16 + khalf * 4;
            #pragma unroll
            for (int r = 0; r < 4; ++r) {
                float v = acc[mi][ni][r] + bv;
                outf[(size_t)(bm + lr + r) * VOC + col] = v;
                Ls[lr + r][col] = v;
            }
        }
    }
    __syncthreads();

    if (tid < 128) {
        int token = bm + tid;
        int tgt = targets[token];
        float m = -1e30f, s = 0.f;
        #pragma unroll 8
        for (int c = 0; c < VOC; ++c) {
            float v = Ls[tid][c];
            float mn = fmaxf(m, v);
            s = s * __expf(m - mn) + __expf(v - mn);
            m = mn;
        }
        red[tid] = m + logf(s) - Ls[tid][tgt];
    }
    __syncthreads();
    if (tid < 64) {
        float s = red[tid] + red[tid + 64];
        #pragma unroll
        for (int off = 32; off > 0; off >>= 1) s += __shfl_xor(s, off);
        if (tid == 0) {
            atomicAdd(&lossbuf[0], s);
            __threadfence();
            int done = atomicAdd(&((int*)lossbuf)[1], 1);
            if (done == (NTOK / 128) - 1) {     // last block
                __threadfence();
                float total = atomicAdd(&lossbuf[0], 0.0f);
                out_loss[0] = total / (float)NTOK;
            }
        }
    }
}

extern "C" void kernel_launch(void* const* d_in, const int* in_sizes, int n_in,
                              void* d_out, int out_size, void* d_ws, size_t ws_size,
                              hipStream_t stream) {
    const int*   idx     = (const int*)  d_in[0];
    const int*   targets = (const int*)  d_in[1];
    const float* tok_emb = (const float*)d_in[2];
    const float* pos_emb = (const float*)d_in[3];
    const float* Wq      = (const float*)d_in[4];
    const float* Wk      = (const float*)d_in[5];
    const float* Wv      = (const float*)d_in[6];
    const float* Wproj   = (const float*)d_in[7];
    const float* bproj   = (const float*)d_in[8];
    const float* W1      = (const float*)d_in[9];
    const float* b1      = (const float*)d_in[10];
    const float* W2      = (const float*)d_in[11];
    const float* b2      = (const float*)d_in[12];
    const float* Wlm     = (const float*)d_in[13];
    const float* blm     = (const float*)d_in[14];

    char* ws = (char*)d_ws;
    bf16*  WprojT = (bf16*) (ws + 0);                       // 24576 B
    float* qkvbuf = (float*)(ws + 25165824);                // 9437184 B
    bf16*  attnT  = (bf16*) (ws + 34603008);                // 2097152 B
    bf16*  xtab   = (bf16*) (ws + 37748736);                // 12779520 B
    bf16*  x3     = (bf16*) (ws + 163577856);               // 25165824 B
    float* lossbuf= (float*)(ws + 188743680);               // [0]=sum, [1]=counter
    u8*    W1f8   = (u8*)   (ws + 188874752);               // 589824 B
    u8*    W2f8   = (u8*)   (ws + 190054400);               // 589824 B
    bf16*  WqkvT  = (bf16*) (ws + 191234048);               // 98304 B
    bf16*  WlmT   = (bf16*) (ws + 191332352);               // 98304 B

    float* out_logits = (float*)d_out;                      // [32768*65] f32
    float* out_loss   = out_logits + (size_t)NTOK * VOC;    // [1]

    pack_all_kernel<<<640 + FFDIM + C_EMB + XROWS / 4, 256, 0, stream>>>(
        Wq, Wk, Wv, Wlm, Wproj, W1, W2, tok_emb, pos_emb,
        WqkvT, WlmT, WprojT, W1f8, W2f8, xtab, lossbuf);

    qkv_gather_kernel<<<NTOK / 128, 512, 0, stream>>>(idx, xtab, WqkvT, qkvbuf);
    attn_kernel<<<NB * NH, T_SEQ, 0, stream>>>(qkvbuf, attnT);

    // proj + FF1 + FF2 fused: attnT -> x3 (x2, h1 stay in LDS), 64-token strips, 2 blocks/CU
    ff_mega_kernel<<<NTOK / 64, 512, 0, stream>>>(attnT, WprojT, bproj,
                                                  W1f8, b1, W2f8, b2, x3);

    // LM head + fused loss + grid loss finish
    lm_loss_kernel<<<NTOK / 128, 512, 0, stream>>>(x3, WlmT, blm, targets,
                                                   out_logits, lossbuf, out_loss, NTOK, C_EMB);
}

// Round 4
// 247.227 us; speedup vs baseline: 1.0316x; 1.0316x over previous
//
#include <hip/hip_runtime.h>
#include <hip/hip_bf16.h>
#include <math.h>

typedef __hip_bfloat16 bf16;
typedef __attribute__((ext_vector_type(8))) short bf16x8;
typedef __attribute__((ext_vector_type(4))) float f32x4;
typedef __attribute__((ext_vector_type(8))) int i32x8;
typedef __attribute__((ext_vector_type(4))) int i32x4;
typedef unsigned char u8;
typedef unsigned int u32;

#define T_SEQ   256
#define C_EMB   384
#define NH      6
#define HS      4
#define NB      128
#define NTOK    (NB * T_SEQ)   // 32768
#define VOC     65
#define FFDIM   1536
#define QKVW    72
#define PROJK   32
#define XROWS   (VOC * T_SEQ)  // 16640

#define X2_SCALE    128.0f
#define W1_SCALE    128.0f
#define FF1_DESCALE (1.0f / (128.0f * 128.0f))
#define H1_SCALE    512.0f
#define W2_SCALE    128.0f
#define FF2_DESCALE (1.0f / (512.0f * 128.0f))

__device__ __forceinline__ float bf2f(bf16 x) { return __bfloat162float(x); }
__device__ __forceinline__ bf16  f2b(float x) { return __float2bfloat16(x); }
__device__ __forceinline__ short f2s(float x) { bf16 b = __float2bfloat16(x); return *reinterpret_cast<short*>(&b); }
__device__ __forceinline__ u8 f2fp8(float x) {
    return (u8)(__builtin_amdgcn_cvt_pk_fp8_f32(x, x, 0, false) & 0xff);
}
__device__ __forceinline__ u32 pk4fp8(const float* w) {
    int p = __builtin_amdgcn_cvt_pk_fp8_f32(w[0], w[1], 0, false);
    p = __builtin_amdgcn_cvt_pk_fp8_f32(w[2], w[3], p, true);
    return (u32)p;
}

// async 16B global->LDS. LDS dst = wave-uniform base + lane*16; global addr per-lane (gather ok).
__device__ __forceinline__ void glds16(const void* g, void* l) {
    __builtin_amdgcn_global_load_lds((const __attribute__((address_space(1))) void*)g,
                                     (__attribute__((address_space(3))) void*)l, 16, 0, 0);
}

// ---------------- all weight packing + embedding table + loss-accumulator init, ONE dispatch
__global__ void pack_all_kernel(const float* __restrict__ Wq, const float* __restrict__ Wk,
                                const float* __restrict__ Wv, const float* __restrict__ Wlm,
                                const float* __restrict__ Wproj,
                                const float* __restrict__ W1, const float* __restrict__ W2,
                                const float* __restrict__ tok_emb, const float* __restrict__ pos_emb,
                                bf16* __restrict__ WqkvT, bf16* __restrict__ WlmT,
                                bf16* __restrict__ WprojT, u8* __restrict__ W1f8,
                                u8* __restrict__ W2f8, bf16* __restrict__ xtab,
                                float* __restrict__ lossbuf) {
    int blk = blockIdx.x;
    if (blk == 0 && threadIdx.x == 0) { lossbuf[0] = 0.f; ((int*)lossbuf)[1] = 0; }
    if (blk < 128) {                                   // WqkvT [128,384]
        int n = blk;
        for (int c = threadIdx.x; c < C_EMB; c += 256) {
            float v = 0.f;
            if (n < QKVW) {
                int sel = n / 24, r = n % 24, h = r >> 2, d = r & 3;
                const float* W = (sel == 0) ? Wq : (sel == 1) ? Wk : Wv;
                v = W[(h * C_EMB + c) * HS + d];
            }
            WqkvT[(size_t)n * C_EMB + c] = f2b(v);
        }
    } else if (blk < 256) {                            // WlmT [128,384]
        int n = blk - 128;
        for (int c = threadIdx.x; c < C_EMB; c += 256)
            WlmT[(size_t)n * C_EMB + c] = f2b(n < VOC ? Wlm[(size_t)c * VOC + n] : 0.f);
    } else if (blk < 640) {                            // WprojT [384,32]
        int n = blk - 256;
        int k = threadIdx.x;
        if (k < PROJK)
            WprojT[(size_t)n * PROJK + k] = f2b(k < 24 ? Wproj[(size_t)k * C_EMB + n] : 0.f);
    } else if (blk < 640 + FFDIM) {                    // W1f8 [1536,384] fp8 * W1_SCALE
        int n = blk - 640;
        for (int k = threadIdx.x; k < C_EMB; k += 256)
            W1f8[(size_t)n * C_EMB + k] = f2fp8(W1[(size_t)k * FFDIM + n] * W1_SCALE);
    } else if (blk < 640 + FFDIM + C_EMB) {            // W2f8 [384,1536] fp8 * W2_SCALE
        int n = blk - 640 - FFDIM;
        for (int k = threadIdx.x; k < FFDIM; k += 256)
            W2f8[(size_t)n * FFDIM + k] = f2fp8(W2[(size_t)k * C_EMB + n] * W2_SCALE);
    } else {                                           // xtab [65*256, 384] bf16
        int base = (blk - (640 + FFDIM + C_EMB)) * 4;
        for (int r = 0; r < 4; ++r) {
            int row = base + r;
            int id = row >> 8, t = row & 255;
            const float* te = tok_emb + (size_t)id * C_EMB;
            const float* pe = pos_emb + (size_t)t * C_EMB;
            bf16* dst = xtab + (size_t)row * C_EMB;
            for (int c = threadIdx.x; c < C_EMB; c += 256)
                dst[c] = f2b(te[c] + pe[c]);
        }
    }
}

// ---------------- QKV gather-GEMM, 512 threads / 8 waves, BK=64 (128B rows, (r&7)*16 rotation)
__global__ __launch_bounds__(512)
void qkv_gather_kernel(const int* __restrict__ idx, const bf16* __restrict__ xtab,
                       const bf16* __restrict__ Bt, float* __restrict__ outf) {
    __shared__ __align__(16) u8 As[16384];   // [128 rows][128B = 64 bf16], row r rotated by (r&7)*16B
    __shared__ __align__(16) u8 Bs[16384];
    __shared__ int rowid[128];
    int tid = threadIdx.x, lane = tid & 63, wave = tid >> 6;
    int bm = blockIdx.x * 128;
    int wm = (wave & 1) * 64, wn = (wave >> 1) * 32;
    int lrow = lane & 15, kq = lane >> 4;
    if (tid < 128) { int token = bm + tid; rowid[tid] = idx[token] * T_SEQ + (token & (T_SEQ - 1)); }
    __syncthreads();

    int r0 = tid >> 3;
    int s0 = (((tid & 7) * 16) - (r0 & 7) * 16) & 127;
    int c1 = tid + 512;
    int r1 = c1 >> 3;
    int s1 = (((c1 & 7) * 16) - (r1 & 7) * 16) & 127;
    const u8* xb = (const u8*)xtab;
    const u8* bb = (const u8*)Bt;
    long gA0 = (long)rowid[r0] * 768 + s0;
    long gA1 = (long)rowid[r1] * 768 + s1;
    long gB0 = (long)r0 * 768 + s0;
    long gB1 = (long)r1 * 768 + s1;
    int ro = (lrow & 7) * 16;

    f32x4 acc[4][2] = {};
    for (int k0 = 0; k0 < 768; k0 += 128) {            // k0 = byte offset within 768B row
        glds16(xb + gA0 + k0, As + (size_t)tid * 16);
        glds16(xb + gA1 + k0, As + (size_t)c1 * 16);
        glds16(bb + gB0 + k0, Bs + (size_t)tid * 16);
        glds16(bb + gB1 + k0, Bs + (size_t)c1 * 16);
        __syncthreads();
        #pragma unroll
        for (int ks = 0; ks < 2; ++ks) {
            int off = (ks * 64 + kq * 16 + ro) & 127;
            bf16x8 af[4], bff[2];
            #pragma unroll
            for (int i = 0; i < 4; ++i)
                af[i] = *(const bf16x8*)&As[(size_t)(wm + i * 16 + lrow) * 128 + off];
            #pragma unroll
            for (int i = 0; i < 2; ++i)
                bff[i] = *(const bf16x8*)&Bs[(size_t)(wn + i * 16 + lrow) * 128 + off];
            #pragma unroll
            for (int mi = 0; mi < 4; ++mi)
                #pragma unroll
                for (int ni = 0; ni < 2; ++ni)
                    acc[mi][ni] = __builtin_amdgcn_mfma_f32_16x16x32_bf16(af[mi], bff[ni], acc[mi][ni], 0, 0, 0);
        }
        __syncthreads();
    }

    #pragma unroll
    for (int ni = 0; ni < 2; ++ni) {
        int col = wn + ni * 16 + lrow;
        if (col >= QKVW) continue;
        #pragma unroll
        for (int mi = 0; mi < 4; ++mi) {
            int orow = bm + wm + mi * 16 + kq * 4;
            #pragma unroll
            for (int r = 0; r < 4; ++r)
                outf[(size_t)(orow + r) * QKVW + col] = acc[mi][ni][r];
        }
    }
}

// ---------------- causal softmax attention (no-max-stabilization form; scores << 1)
__global__ void attn_kernel(const float* __restrict__ qkv,
                            bf16* __restrict__ attnT) {
    int bh = blockIdx.x;
    int b = bh / NH, h = bh % NH;
    int t = threadIdx.x;
    __shared__ float4 kv[T_SEQ][2];    // [s][0]=k4, [s][1]=v4
    const float* base = qkv + (size_t)(b * T_SEQ) * QKVW;
    kv[t][0] = *(const float4*)(base + t * QKVW + 24 + h * HS);
    kv[t][1] = *(const float4*)(base + t * QKVW + 48 + h * HS);
    __syncthreads();
    const float scale = 0.05103103630798288f;   // 384^-0.5
    float4 q = *(const float4*)(base + t * QKVW + h * HS);
    float qx = q.x * scale, qy = q.y * scale, qz = q.z * scale, qw = q.w * scale;
    float sum0 = 0.f, sum1 = 0.f;
    float o0x = 0.f, o0y = 0.f, o0z = 0.f, o0w = 0.f;
    float o1x = 0.f, o1y = 0.f, o1z = 0.f, o1w = 0.f;
    int s = 0;
    for (; s + 1 <= t; s += 2) {
        float4 k0 = kv[s][0],     v0 = kv[s][1];
        float4 k1 = kv[s + 1][0], v1 = kv[s + 1][1];
        float p0 = __expf(qx * k0.x + qy * k0.y + qz * k0.z + qw * k0.w);
        float p1 = __expf(qx * k1.x + qy * k1.y + qz * k1.z + qw * k1.w);
        sum0 += p0; sum1 += p1;
        o0x += p0 * v0.x; o0y += p0 * v0.y; o0z += p0 * v0.z; o0w += p0 * v0.w;
        o1x += p1 * v1.x; o1y += p1 * v1.y; o1z += p1 * v1.z; o1w += p1 * v1.w;
    }
    if (s <= t) {
        float4 k0 = kv[s][0], v0 = kv[s][1];
        float p0 = __expf(qx * k0.x + qy * k0.y + qz * k0.z + qw * k0.w);
        sum0 += p0;
        o0x += p0 * v0.x; o0y += p0 * v0.y; o0z += p0 * v0.z; o0w += p0 * v0.w;
    }
    float inv = 1.f / (sum0 + sum1);
    bf16* out = attnT + (size_t)(b * T_SEQ + t) * PROJK + h * HS;
    out[0] = f2b((o0x + o1x) * inv);
    out[1] = f2b((o0y + o1y) * inv);
    out[2] = f2b((o0z + o1z) * inv);
    out[3] = f2b((o0w + o1w) * inv);
    if (h == 0) {
        bf16* pad = attnT + (size_t)(b * T_SEQ + t) * PROJK + 24;
        *(uint4*)pad = uint4{0, 0, 0, 0};
    }
}

// ---------------- MEGA v3: proj + FF1 + FF2 fused, 128-token strip, 144 KB LDS, 1 block/CU.
// LDS-traffic-optimized: FF1 N-chunk = 256 (nt=6) halves x2 re-reads and barrier count;
// W2 fragments stream global->reg from L2 (no bs2 LDS buffer -> off the LDS pipe).
// x2 and h1 never touch HBM.
__global__ __launch_bounds__(512, 2)
void ff_mega_kernel(const bf16* __restrict__ attnT, const bf16* __restrict__ WprojT,
                    const float* __restrict__ bproj,
                    const u8* __restrict__ W1f8, const float* __restrict__ b1,
                    const u8* __restrict__ W2f8, const float* __restrict__ b2,
                    bf16* __restrict__ x3) {
    __shared__ __align__(16) u8 smem[147456];          // 144 KB
    u8* x2_lds = smem;                                 // [3][128][128] fp8, (m&7)*16 rotation
    u8* bs1    = smem + 49152;                         // 2 x 32KB W1 chunk dbuf ([256 n][128 k])
    u8* h1t    = smem + 114688;                        // [128][256] fp8, (m&7)*16 rotation mod 256
    short* As_p = (short*)(smem + 49152);              // proj attn tile [128][32]sh (alias bs1)
    short* Bs_p = (short*)(smem + 57344);              // proj Wproj tile [384][32]sh (alias bs1)

    int tid  = threadIdx.x;
    int lane = tid & 63;
    int wave = tid >> 6;
    int bm   = blockIdx.x * 128;
    int lrow  = lane & 15;
    int khalf = lane >> 4;
    int wm  = (wave & 1) * 64;                         // M half: 2 x 64 rows
    int wn6 = (wave >> 1) * 96;                        // 384-wide N quarter (proj, FF2)
    int wn4 = (wave >> 1) * 64;                        // 256-wide N quarter (FF1)

    // ---- proj staging: A [128][32]sh, B [384][32]sh
    {
        int row = tid >> 2;
        int i0 = (tid & 3) * 16;
        int selem = ((i0 - ((row >> 1) & 3) * 16) & 63) >> 1;
        glds16(attnT + (size_t)(bm + row) * PROJK + selem, As_p + (size_t)tid * 8);
        #pragma unroll
        for (int p = 0; p < 3; ++p) {
            int c = tid + p * 512;
            int rowb = c >> 2;
            int sel2 = (((c & 3) * 16 - ((rowb >> 1) & 3) * 16) & 63) >> 1;
            glds16(WprojT + (size_t)rowb * PROJK + sel2, Bs_p + (size_t)c * 8);
        }
    }
    __syncthreads();

    // ---- proj compute (K=32, one MFMA step), swapped operands
    f32x4 accp[4][6] = {};
    {
        int arot16 = ((lrow >> 1) & 3) * 16;
        int roff = ((khalf * 16 + arot16) & 63) >> 1;
        bf16x8 afp[4], bfp[6];
        #pragma unroll
        for (int i = 0; i < 4; ++i)
            afp[i] = *(const bf16x8*)&As_p[(size_t)(wm + i * 16 + lrow) * 32 + roff];
        #pragma unroll
        for (int i = 0; i < 6; ++i)
            bfp[i] = *(const bf16x8*)&Bs_p[(size_t)(wn6 + i * 16 + lrow) * 32 + roff];
        #pragma unroll
        for (int mi = 0; mi < 4; ++mi)
            #pragma unroll
            for (int ni = 0; ni < 6; ++ni)
                accp[mi][ni] = __builtin_amdgcn_mfma_f32_16x16x32_bf16(bfp[ni], afp[mi], accp[mi][ni], 0, 0, 0);
    }
    __syncthreads();                                   // all proj LDS reads done (bs1 alias safe)

    // issue W1 chunk 0 (nt=0,kk=0) into buf0: 32 KB, flies under the proj epilogue
    #pragma unroll
    for (int p = 0; p < 4; ++p) {
        int c = tid + p * 512;
        int row = c >> 3;
        int sr = (((c & 7) * 16) - (row & 7) * 16) & 127;
        glds16(W1f8 + (size_t)row * 384 + sr, bs1 + (size_t)c * 16);
    }

    // proj epilogue -> x2_lds (fp8 * X2_SCALE, rotated)
    #pragma unroll
    for (int mi = 0; mi < 4; ++mi) {
        int m = wm + mi * 16 + lrow;
        #pragma unroll
        for (int ni = 0; ni < 6; ++ni) {
            int n0 = wn6 + ni * 16 + khalf * 4;
            float4 bv = *(const float4*)(bproj + n0);
            float w[4];
            w[0] = (accp[mi][ni][0] + bv.x) * X2_SCALE;
            w[1] = (accp[mi][ni][1] + bv.y) * X2_SCALE;
            w[2] = (accp[mi][ni][2] + bv.z) * X2_SCALE;
            w[3] = (accp[mi][ni][3] + bv.w) * X2_SCALE;
            *(u32*)&x2_lds[(size_t)(n0 >> 7) * 16384 + (size_t)m * 128 +
                           (((n0 & 127) + (m & 7) * 16) & 127)] = pk4fp8(w);
        }
    }
    __syncthreads();                                   // x2 ready, bs1 buf0 ready

    int arot8 = (lrow & 7) * 16;
    int off0 = (khalf * 32 + arot8) & 127;
    int off1 = (off0 + 16) & 127;

    f32x4 acc1[4][4] = {};
    f32x4 acc2[4][6] = {};

    for (int nt = 0; nt < 6; ++nt) {
        // ---- FF1: 3 K-steps (K=384), N-chunk 256, W1 dbuf with prefetch
        #pragma unroll
        for (int kk = 0; kk < 3; ++kk) {
            int stp = nt * 3 + kk;
            if (stp + 1 < 18) {                        // prefetch next 32KB W1 chunk
                int nnt = (stp + 1) / 3, nk0 = ((stp + 1) % 3) * 128;
                u8* dst = bs1 + (size_t)((stp + 1) & 1) * 32768;
                #pragma unroll
                for (int p = 0; p < 4; ++p) {
                    int c = tid + p * 512;
                    int row = c >> 3;
                    int sr = (((c & 7) * 16) - (row & 7) * 16) & 127;
                    glds16(W1f8 + (size_t)(nnt * 256 + row) * 384 + nk0 + sr,
                           dst + (size_t)c * 16);
                }
            }
            const u8* abase = x2_lds + (size_t)kk * 16384;
            const u8* bbase = bs1 + (size_t)(stp & 1) * 32768;
            i32x8 a[4];
            #pragma unroll
            for (int i = 0; i < 4; ++i) {
                const u8* rp = abase + (size_t)(wm + i * 16 + lrow) * 128;
                i32x4 lo = *(const i32x4*)(rp + off0);
                i32x4 hi = *(const i32x4*)(rp + off1);
                a[i][0]=lo[0]; a[i][1]=lo[1]; a[i][2]=lo[2]; a[i][3]=lo[3];
                a[i][4]=hi[0]; a[i][5]=hi[1]; a[i][6]=hi[2]; a[i][7]=hi[3];
            }
            #pragma unroll
            for (int nh = 0; nh < 2; ++nh) {           // b-frags in halves (VGPR cap)
                i32x8 b[2];
                #pragma unroll
                for (int j = 0; j < 2; ++j) {
                    int ni = nh * 2 + j;
                    const u8* rp = bbase + (size_t)(wn4 + ni * 16 + lrow) * 128;
                    i32x4 lo = *(const i32x4*)(rp + off0);
                    i32x4 hi = *(const i32x4*)(rp + off1);
                    b[j][0]=lo[0]; b[j][1]=lo[1]; b[j][2]=lo[2]; b[j][3]=lo[3];
                    b[j][4]=hi[0]; b[j][5]=hi[1]; b[j][6]=hi[2]; b[j][7]=hi[3];
                }
                #pragma unroll
                for (int mi = 0; mi < 4; ++mi)
                    #pragma unroll
                    for (int j = 0; j < 2; ++j)
                        acc1[mi][nh * 2 + j] = __builtin_amdgcn_mfma_scale_f32_16x16x128_f8f6f4(
                            b[j], a[mi], acc1[mi][nh * 2 + j], 0, 0,
                            0, 0x7f7f7f7f, 0, 0x7f7f7f7f);
            }
            __syncthreads();
        }

        // ---- h1 epilogue -> h1t [128][256] (fp8 * H1_SCALE, relu, rotated); zero acc1
        #pragma unroll
        for (int mi = 0; mi < 4; ++mi) {
            int m = wm + mi * 16 + lrow;
            #pragma unroll
            for (int ni = 0; ni < 4; ++ni) {
                int n0 = wn4 + ni * 16 + khalf * 4;
                float4 bv = *(const float4*)(b1 + nt * 256 + n0);
                float w[4];
                w[0] = fmaxf(acc1[mi][ni][0] * FF1_DESCALE + bv.x, 0.f) * H1_SCALE;
                w[1] = fmaxf(acc1[mi][ni][1] * FF1_DESCALE + bv.y, 0.f) * H1_SCALE;
                w[2] = fmaxf(acc1[mi][ni][2] * FF1_DESCALE + bv.z, 0.f) * H1_SCALE;
                w[3] = fmaxf(acc1[mi][ni][3] * FF1_DESCALE + bv.w, 0.f) * H1_SCALE;
                *(u32*)&h1t[(size_t)m * 256 + ((n0 + (m & 7) * 16) & 255)] = pk4fp8(w);
                acc1[mi][ni] = f32x4{0.f, 0.f, 0.f, 0.f};
            }
        }
        __syncthreads();                               // h1t ready

        // ---- FF2 partial: acc2 += h1t @ W2[k 256-slice nt], 2 sub-k of 128;
        //      W2 frags global->reg (L2-resident), b-frags in halves of 3
        #pragma unroll
        for (int sk = 0; sk < 2; ++sk) {
            i32x8 a2[4];
            #pragma unroll
            for (int i = 0; i < 4; ++i) {
                const u8* rp = h1t + (size_t)(wm + i * 16 + lrow) * 256;
                int o0 = (sk * 128 + khalf * 32 + arot8) & 255;
                int o1 = (sk * 128 + khalf * 32 + 16 + arot8) & 255;
                i32x4 lo = *(const i32x4*)(rp + o0);
                i32x4 hi = *(const i32x4*)(rp + o1);
                a2[i][0]=lo[0]; a2[i][1]=lo[1]; a2[i][2]=lo[2]; a2[i][3]=lo[3];
                a2[i][4]=hi[0]; a2[i][5]=hi[1]; a2[i][6]=hi[2]; a2[i][7]=hi[3];
            }
            #pragma unroll
            for (int half = 0; half < 2; ++half) {
                i32x8 bw[3];
                #pragma unroll
                for (int j = 0; j < 3; ++j) {
                    int n = wn6 + (half * 3 + j) * 16 + lrow;
                    const u8* p = W2f8 + (size_t)n * 1536 + nt * 256 + sk * 128 + khalf * 32;
                    i32x4 lo = *(const i32x4*)p;
                    i32x4 hi = *(const i32x4*)(p + 16);
                    bw[j][0]=lo[0]; bw[j][1]=lo[1]; bw[j][2]=lo[2]; bw[j][3]=lo[3];
                    bw[j][4]=hi[0]; bw[j][5]=hi[1]; bw[j][6]=hi[2]; bw[j][7]=hi[3];
                }
                #pragma unroll
                for (int mi = 0; mi < 4; ++mi)
                    #pragma unroll
                    for (int j = 0; j < 3; ++j)
                        acc2[mi][half * 3 + j] = __builtin_amdgcn_mfma_scale_f32_16x16x128_f8f6f4(
                            bw[j], a2[mi], acc2[mi][half * 3 + j], 0, 0,
                            0, 0x7f7f7f7f, 0, 0x7f7f7f7f);
            }
        }
        __syncthreads();                               // h1t reads done before next nt write
    }

    // ---- x3 epilogue: bf16 via rotated LDS [128 rows][3 chunks][256B], coalesced stores
    u8* Ep = smem;                                     // 96KB overlay (x2/bs1/h1t all dead)
    #pragma unroll
    for (int mi = 0; mi < 4; ++mi) {
        int m = wm + mi * 16 + lrow;
        #pragma unroll
        for (int ni = 0; ni < 6; ++ni) {
            int n0 = wn6 + ni * 16 + khalf * 4;
            float4 bv = *(const float4*)(b2 + n0);
            union { short s[4]; uint2 u; } pk;
            pk.s[0] = f2s(acc2[mi][ni][0] * FF2_DESCALE + bv.x);
            pk.s[1] = f2s(acc2[mi][ni][1] * FF2_DESCALE + bv.y);
            pk.s[2] = f2s(acc2[mi][ni][2] * FF2_DESCALE + bv.z);
            pk.s[3] = f2s(acc2[mi][ni][3] * FF2_DESCALE + bv.w);
            *(uint2*)&Ep[(size_t)m * 768 + ((n0 >> 7) << 8) +
                         ((((n0 & 127) * 2) + (m & 7) * 16) & 255)] = pk.u;
        }
    }
    __syncthreads();
    #pragma unroll
    for (int p = 0; p < 12; ++p) {
        int c = tid + p * 512;
        int row = c / 48;
        int sl = c - row * 48;
        int g0 = sl * 16;
        int chunk = g0 >> 8;
        int loc = g0 & 255;
        uint4 v = *(const uint4*)&Ep[(size_t)row * 768 + (chunk << 8) +
                                     ((loc + (row & 7) * 16) & 255)];
        *(uint4*)((u8*)x3 + (size_t)(bm + row) * 768 + g0) = v;
    }
}

// ---------------- LM head + fused CE loss + grid-level loss finish (atomics)
__global__ __launch_bounds__(512)
void lm_loss_kernel(const bf16* __restrict__ A, const bf16* __restrict__ Bt,
                    const float* __restrict__ bias, const int* __restrict__ targets,
                    float* __restrict__ outf, float* __restrict__ lossbuf,
                    float* __restrict__ out_loss, int M, int K) {
    __shared__ short As[128][32];
    __shared__ short Bs[128][32];
    __shared__ float Ls[128][66];
    __shared__ float red[128];
    int tid  = threadIdx.x;
    int lane = tid & 63;
    int wave = tid >> 6;
    int bm = blockIdx.x * 128;
    int wm = (wave & 1) * 64;
    int wn = (wave >> 1) * 32;
    int lrow  = lane & 15;
    int khalf = lane >> 4;

    int row = tid >> 2;
    int i0 = (tid & 3) * 16;
    int selem = ((i0 - ((row >> 1) & 3) * 16) & 63) >> 1;
    int arot = ((lrow >> 1) & 3) * 16;
    int roff = ((khalf * 16 + arot) & 63) >> 1;

    f32x4 acc[4][2] = {};
    for (int k0 = 0; k0 < K; k0 += 32) {
        glds16(A  + (size_t)(bm + row) * K + k0 + selem, (short*)As + (size_t)tid * 8);
        glds16(Bt + (size_t)row * K + k0 + selem,        (short*)Bs + (size_t)tid * 8);
        __syncthreads();

        bf16x8 af[4], bff[2];
        #pragma unroll
        for (int i = 0; i < 4; ++i)
            af[i] = *(const bf16x8*)&As[wm + i * 16 + lrow][roff];
        #pragma unroll
        for (int i = 0; i < 2; ++i)
            bff[i] = *(const bf16x8*)&Bs[wn + i * 16 + lrow][roff];
        #pragma unroll
        for (int mi = 0; mi < 4; ++mi)
            #pragma unroll
            for (int ni = 0; ni < 2; ++ni)
                acc[mi][ni] = __builtin_amdgcn_mfma_f32_16x16x32_bf16(af[mi], bff[ni], acc[mi][ni], 0, 0, 0);
        __syncthreads();
    }

    #pragma unroll
    for (int ni = 0; ni < 2; ++ni) {
        int col = wn + ni * 16 + lrow;
        if (col >= VOC) continue;
        float bv = bias[col];
        #pragma unroll
        for (int mi = 0; mi < 4; ++mi) {
            int lr = wm + mi * 16 + khalf * 4;
            #pragma unroll
            for (int r = 0; r < 4; ++r) {
                float v = acc[mi][ni][r] + bv;
                outf[(size_t)(bm + lr + r) * VOC + col] = v;
                Ls[lr + r][col] = v;
            }
        }
    }
    __syncthreads();

    if (tid < 128) {
        int token = bm + tid;
        int tgt = targets[token];
        float m = -1e30f, s = 0.f;
        #pragma unroll 8
        for (int c = 0; c < VOC; ++c) {
            float v = Ls[tid][c];
            float mn = fmaxf(m, v);
            s = s * __expf(m - mn) + __expf(v - mn);
            m = mn;
        }
        red[tid] = m + logf(s) - Ls[tid][tgt];
    }
    __syncthreads();
    if (tid < 64) {
        float s = red[tid] + red[tid + 64];
        #pragma unroll
        for (int off = 32; off > 0; off >>= 1) s += __shfl_xor(s, off);
        if (tid == 0) {
            atomicAdd(&lossbuf[0], s);
            __threadfence();
            int done = atomicAdd(&((int*)lossbuf)[1], 1);
            if (done == (NTOK / 128) - 1) {     // last block
                __threadfence();
                float total = atomicAdd(&lossbuf[0], 0.0f);
                out_loss[0] = total / (float)NTOK;
            }
        }
    }
}

extern "C" void kernel_launch(void* const* d_in, const int* in_sizes, int n_in,
                              void* d_out, int out_size, void* d_ws, size_t ws_size,
                              hipStream_t stream) {
    const int*   idx     = (const int*)  d_in[0];
    const int*   targets = (const int*)  d_in[1];
    const float* tok_emb = (const float*)d_in[2];
    const float* pos_emb = (const float*)d_in[3];
    const float* Wq      = (const float*)d_in[4];
    const float* Wk      = (const float*)d_in[5];
    const float* Wv      = (const float*)d_in[6];
    const float* Wproj   = (const float*)d_in[7];
    const float* bproj   = (const float*)d_in[8];
    const float* W1      = (const float*)d_in[9];
    const float* b1      = (const float*)d_in[10];
    const float* W2      = (const float*)d_in[11];
    const float* b2      = (const float*)d_in[12];
    const float* Wlm     = (const float*)d_in[13];
    const float* blm     = (const float*)d_in[14];

    char* ws = (char*)d_ws;
    bf16*  WprojT = (bf16*) (ws + 0);                       // 24576 B
    float* qkvbuf = (float*)(ws + 25165824);                // 9437184 B
    bf16*  attnT  = (bf16*) (ws + 34603008);                // 2097152 B
    bf16*  xtab   = (bf16*) (ws + 37748736);                // 12779520 B
    bf16*  x3     = (bf16*) (ws + 163577856);               // 25165824 B
    float* lossbuf= (float*)(ws + 188743680);               // [0]=sum, [1]=counter
    u8*    W1f8   = (u8*)   (ws + 188874752);               // 589824 B
    u8*    W2f8   = (u8*)   (ws + 190054400);               // 589824 B
    bf16*  WqkvT  = (bf16*) (ws + 191234048);               // 98304 B
    bf16*  WlmT   = (bf16*) (ws + 191332352);               // 98304 B

    float* out_logits = (float*)d_out;                      // [32768*65] f32
    float* out_loss   = out_logits + (size_t)NTOK * VOC;    // [1]

    pack_all_kernel<<<640 + FFDIM + C_EMB + XROWS / 4, 256, 0, stream>>>(
        Wq, Wk, Wv, Wlm, Wproj, W1, W2, tok_emb, pos_emb,
        WqkvT, WlmT, WprojT, W1f8, W2f8, xtab, lossbuf);

    qkv_gather_kernel<<<NTOK / 128, 512, 0, stream>>>(idx, xtab, WqkvT, qkvbuf);
    attn_kernel<<<NB * NH, T_SEQ, 0, stream>>>(qkvbuf, attnT);

    // proj + FF1 + FF2 fused: attnT -> x3 (x2, h1 stay in LDS), 128-token strips
    ff_mega_kernel<<<NTOK / 128, 512, 0, stream>>>(attnT, WprojT, bproj,
                                                   W1f8, b1, W2f8, b2, x3);

    // LM head + fused loss + grid loss finish
    lm_loss_kernel<<<NTOK / 128, 512, 0, stream>>>(x3, WlmT, blm, targets,
                                                   out_logits, lossbuf, out_loss, NTOK, C_EMB);
}

// Round 5
// 214.110 us; speedup vs baseline: 1.1912x; 1.1547x over previous
//
#include <hip/hip_runtime.h>
#include <hip/hip_bf16.h>
#include <math.h>

typedef __hip_bfloat16 bf16;
typedef __attribute__((ext_vector_type(8))) short bf16x8;
typedef __attribute__((ext_vector_type(4))) float f32x4;
typedef __attribute__((ext_vector_type(8))) int i32x8;
typedef __attribute__((ext_vector_type(4))) int i32x4;
typedef unsigned char u8;
typedef unsigned int u32;

#define T_SEQ   256
#define C_EMB   384
#define NH      6
#define HS      4
#define NB      128
#define NTOK    (NB * T_SEQ)   // 32768
#define VOC     65
#define FFDIM   1536
#define QKVW    72
#define PROJK   32
#define XROWS   (VOC * T_SEQ)  // 16640

#define X2_SCALE    128.0f
#define W1_SCALE    128.0f
#define FF1_DESCALE (1.0f / (128.0f * 128.0f))
#define H1_SCALE    512.0f
#define W2_SCALE    128.0f
#define FF2_DESCALE (1.0f / (512.0f * 128.0f))

__device__ __forceinline__ float bf2f(bf16 x) { return __bfloat162float(x); }
__device__ __forceinline__ bf16  f2b(float x) { return __float2bfloat16(x); }
__device__ __forceinline__ short f2s(float x) { bf16 b = __float2bfloat16(x); return *reinterpret_cast<short*>(&b); }
__device__ __forceinline__ u8 f2fp8(float x) {
    return (u8)(__builtin_amdgcn_cvt_pk_fp8_f32(x, x, 0, false) & 0xff);
}
__device__ __forceinline__ u32 pk4fp8(const float* w) {
    int p = __builtin_amdgcn_cvt_pk_fp8_f32(w[0], w[1], 0, false);
    p = __builtin_amdgcn_cvt_pk_fp8_f32(w[2], w[3], p, true);
    return (u32)p;
}

// async 16B global->LDS. LDS dst = wave-uniform base + lane*16; global addr per-lane (gather ok).
__device__ __forceinline__ void glds16(const void* g, void* l) {
    __builtin_amdgcn_global_load_lds((const __attribute__((address_space(1))) void*)g,
                                     (__attribute__((address_space(3))) void*)l, 16, 0, 0);
}

// ---------------- all weight packing + embedding table + loss-accumulator init, ONE dispatch
// W1P/W2P are FRAG-MAJOR: for each (n16 = 16-row n-group, k-chunk of 128), a 2KB block holding
// lane l's 32-byte MFMA fragment at offset l*32: n = n16*16 + (l&15), k = kchunk*128+(l>>4)*32+j.
// A wave's b-frag load is then one contiguous 2KB block (perfectly coalesced, L2-hot).
__global__ void pack_all_kernel(const float* __restrict__ Wq, const float* __restrict__ Wk,
                                const float* __restrict__ Wv, const float* __restrict__ Wlm,
                                const float* __restrict__ Wproj,
                                const float* __restrict__ W1, const float* __restrict__ W2,
                                const float* __restrict__ tok_emb, const float* __restrict__ pos_emb,
                                bf16* __restrict__ WqkvT, bf16* __restrict__ WlmT,
                                bf16* __restrict__ WprojT, u8* __restrict__ W1P,
                                u8* __restrict__ W2P, bf16* __restrict__ xtab,
                                float* __restrict__ lossbuf) {
    int blk = blockIdx.x;
    int t = threadIdx.x;
    if (blk == 0 && t == 0) { lossbuf[0] = 0.f; ((int*)lossbuf)[1] = 0; }
    if (blk < 128) {                                   // WqkvT [128,384]
        int n = blk;
        for (int c = t; c < C_EMB; c += 256) {
            float v = 0.f;
            if (n < QKVW) {
                int sel = n / 24, r = n % 24, h = r >> 2, d = r & 3;
                const float* W = (sel == 0) ? Wq : (sel == 1) ? Wk : Wv;
                v = W[(h * C_EMB + c) * HS + d];
            }
            WqkvT[(size_t)n * C_EMB + c] = f2b(v);
        }
    } else if (blk < 256) {                            // WlmT [128,384]
        int n = blk - 128;
        for (int c = t; c < C_EMB; c += 256)
            WlmT[(size_t)n * C_EMB + c] = f2b(n < VOC ? Wlm[(size_t)c * VOC + n] : 0.f);
    } else if (blk < 640) {                            // WprojT [384,32]
        int n = blk - 256;
        int k = t;
        if (k < PROJK)
            WprojT[(size_t)n * PROJK + k] = f2b(k < 24 ? Wproj[(size_t)k * C_EMB + n] : 0.f);
    } else if (blk < 640 + 288) {                      // W1P frag-major: 96 n16 x 3 kk x 2KB
        int fb = blk - 640;
        int n16 = fb / 3, kk = fb % 3;
        int b0 = t * 8;                                // 8 bytes per thread
        int l = b0 >> 5;
        int j0 = b0 & 31;
        int n = n16 * 16 + (l & 15);
        int kb = kk * 128 + (l >> 4) * 32 + j0;
        union { u8 b[8]; uint2 u; } pk;
        #pragma unroll
        for (int e = 0; e < 8; ++e)
            pk.b[e] = f2fp8(W1[(size_t)(kb + e) * FFDIM + n] * W1_SCALE);
        *(uint2*)&W1P[(size_t)fb * 2048 + b0] = pk.u;
    } else if (blk < 640 + 576) {                      // W2P frag-major: 24 n16 x 12 kc x 2KB
        int fb = blk - 640 - 288;
        int n16 = fb / 12, kc = fb % 12;
        int b0 = t * 8;
        int l = b0 >> 5;
        int j0 = b0 & 31;
        int n = n16 * 16 + (l & 15);
        int kb = kc * 128 + (l >> 4) * 32 + j0;
        union { u8 b[8]; uint2 u; } pk;
        #pragma unroll
        for (int e = 0; e < 8; ++e)
            pk.b[e] = f2fp8(W2[(size_t)(kb + e) * C_EMB + n] * W2_SCALE);
        *(uint2*)&W2P[(size_t)fb * 2048 + b0] = pk.u;
    } else {                                           // xtab [65*256, 384] bf16
        int base = (blk - (640 + 576)) * 4;
        for (int r = 0; r < 4; ++r) {
            int row = base + r;
            int id = row >> 8, tt = row & 255;
            const float* te = tok_emb + (size_t)id * C_EMB;
            const float* pe = pos_emb + (size_t)tt * C_EMB;
            bf16* dst = xtab + (size_t)row * C_EMB;
            for (int c = t; c < C_EMB; c += 256)
                dst[c] = f2b(te[c] + pe[c]);
        }
    }
}

// ---------------- QKV gather-GEMM, 512 threads / 8 waves, BK=64 (128B rows, (r&7)*16 rotation)
__global__ __launch_bounds__(512)
void qkv_gather_kernel(const int* __restrict__ idx, const bf16* __restrict__ xtab,
                       const bf16* __restrict__ Bt, float* __restrict__ outf) {
    __shared__ __align__(16) u8 As[16384];   // [128 rows][128B = 64 bf16], row r rotated by (r&7)*16B
    __shared__ __align__(16) u8 Bs[16384];
    __shared__ int rowid[128];
    int tid = threadIdx.x, lane = tid & 63, wave = tid >> 6;
    int bm = blockIdx.x * 128;
    int wm = (wave & 1) * 64, wn = (wave >> 1) * 32;
    int lrow = lane & 15, kq = lane >> 4;
    if (tid < 128) { int token = bm + tid; rowid[tid] = idx[token] * T_SEQ + (token & (T_SEQ - 1)); }
    __syncthreads();

    int r0 = tid >> 3;
    int s0 = (((tid & 7) * 16) - (r0 & 7) * 16) & 127;
    int c1 = tid + 512;
    int r1 = c1 >> 3;
    int s1 = (((c1 & 7) * 16) - (r1 & 7) * 16) & 127;
    const u8* xb = (const u8*)xtab;
    const u8* bb = (const u8*)Bt;
    long gA0 = (long)rowid[r0] * 768 + s0;
    long gA1 = (long)rowid[r1] * 768 + s1;
    long gB0 = (long)r0 * 768 + s0;
    long gB1 = (long)r1 * 768 + s1;
    int ro = (lrow & 7) * 16;

    f32x4 acc[4][2] = {};
    for (int k0 = 0; k0 < 768; k0 += 128) {            // k0 = byte offset within 768B row
        glds16(xb + gA0 + k0, As + (size_t)tid * 16);
        glds16(xb + gA1 + k0, As + (size_t)c1 * 16);
        glds16(bb + gB0 + k0, Bs + (size_t)tid * 16);
        glds16(bb + gB1 + k0, Bs + (size_t)c1 * 16);
        __syncthreads();
        #pragma unroll
        for (int ks = 0; ks < 2; ++ks) {
            int off = (ks * 64 + kq * 16 + ro) & 127;
            bf16x8 af[4], bff[2];
            #pragma unroll
            for (int i = 0; i < 4; ++i)
                af[i] = *(const bf16x8*)&As[(size_t)(wm + i * 16 + lrow) * 128 + off];
            #pragma unroll
            for (int i = 0; i < 2; ++i)
                bff[i] = *(const bf16x8*)&Bs[(size_t)(wn + i * 16 + lrow) * 128 + off];
            #pragma unroll
            for (int mi = 0; mi < 4; ++mi)
                #pragma unroll
                for (int ni = 0; ni < 2; ++ni)
                    acc[mi][ni] = __builtin_amdgcn_mfma_f32_16x16x32_bf16(af[mi], bff[ni], acc[mi][ni], 0, 0, 0);
        }
        __syncthreads();
    }

    #pragma unroll
    for (int ni = 0; ni < 2; ++ni) {
        int col = wn + ni * 16 + lrow;
        if (col >= QKVW) continue;
        #pragma unroll
        for (int mi = 0; mi < 4; ++mi) {
            int orow = bm + wm + mi * 16 + kq * 4;
            #pragma unroll
            for (int r = 0; r < 4; ++r)
                outf[(size_t)(orow + r) * QKVW + col] = acc[mi][ni][r];
        }
    }
}

// ---------------- causal softmax attention (no-max-stabilization form; scores << 1)
__global__ void attn_kernel(const float* __restrict__ qkv,
                            bf16* __restrict__ attnT) {
    int bh = blockIdx.x;
    int b = bh / NH, h = bh % NH;
    int t = threadIdx.x;
    __shared__ float4 kv[T_SEQ][2];    // [s][0]=k4, [s][1]=v4
    const float* base = qkv + (size_t)(b * T_SEQ) * QKVW;
    kv[t][0] = *(const float4*)(base + t * QKVW + 24 + h * HS);
    kv[t][1] = *(const float4*)(base + t * QKVW + 48 + h * HS);
    __syncthreads();
    const float scale = 0.05103103630798288f;   // 384^-0.5
    float4 q = *(const float4*)(base + t * QKVW + h * HS);
    float qx = q.x * scale, qy = q.y * scale, qz = q.z * scale, qw = q.w * scale;
    float sum0 = 0.f, sum1 = 0.f;
    float o0x = 0.f, o0y = 0.f, o0z = 0.f, o0w = 0.f;
    float o1x = 0.f, o1y = 0.f, o1z = 0.f, o1w = 0.f;
    int s = 0;
    for (; s + 1 <= t; s += 2) {
        float4 k0 = kv[s][0],     v0 = kv[s][1];
        float4 k1 = kv[s + 1][0], v1 = kv[s + 1][1];
        float p0 = __expf(qx * k0.x + qy * k0.y + qz * k0.z + qw * k0.w);
        float p1 = __expf(qx * k1.x + qy * k1.y + qz * k1.z + qw * k1.w);
        sum0 += p0; sum1 += p1;
        o0x += p0 * v0.x; o0y += p0 * v0.y; o0z += p0 * v0.z; o0w += p0 * v0.w;
        o1x += p1 * v1.x; o1y += p1 * v1.y; o1z += p1 * v1.z; o1w += p1 * v1.w;
    }
    if (s <= t) {
        float4 k0 = kv[s][0], v0 = kv[s][1];
        float p0 = __expf(qx * k0.x + qy * k0.y + qz * k0.z + qw * k0.w);
        sum0 += p0;
        o0x += p0 * v0.x; o0y += p0 * v0.y; o0z += p0 * v0.z; o0w += p0 * v0.w;
    }
    float inv = 1.f / (sum0 + sum1);
    bf16* out = attnT + (size_t)(b * T_SEQ + t) * PROJK + h * HS;
    out[0] = f2b((o0x + o1x) * inv);
    out[1] = f2b((o0y + o1y) * inv);
    out[2] = f2b((o0z + o1z) * inv);
    out[3] = f2b((o0w + o1w) * inv);
    if (h == 0) {
        bf16* pad = attnT + (size_t)(b * T_SEQ + t) * PROJK + 24;
        *(uint4*)pad = uint4{0, 0, 0, 0};
    }
}

// ---------------- MEGA v4: proj + FF1 + FF2 fused, 128-token strip, 96 KB LDS.
// B-operands (W1,W2) NEVER touch LDS: coalesced frag-major global->reg loads (L2-hot).
// LDS holds only x2 (48K) + h1t (32K). FF1's 3-kk loop is barrier-free; 2 barriers/nt.
// x2 and h1 never touch HBM. MFMA order identical to prior rounds (bitwise-same output).
__global__ __launch_bounds__(512, 2)
void ff_mega_kernel(const bf16* __restrict__ attnT, const bf16* __restrict__ WprojT,
                    const float* __restrict__ bproj,
                    const u8* __restrict__ W1P, const float* __restrict__ b1,
                    const u8* __restrict__ W2P, const float* __restrict__ b2,
                    bf16* __restrict__ x3) {
    __shared__ __align__(16) u8 smem[98304];           // 96 KB
    u8* x2_lds = smem;                                 // [3][128][128] fp8, (m&7)*16 rotation
    u8* h1t    = smem + 49152;                         // [128][256] fp8, (m&7)*16 rotation mod 256
    short* As_p = (short*)(smem + 49152);              // proj attn tile [128][32]sh (alias h1t)
    short* Bs_p = (short*)(smem + 57344);              // proj Wproj tile [384][32]sh (alias h1t)

    int tid  = threadIdx.x;
    int lane = tid & 63;
    int wave = tid >> 6;
    int bm   = blockIdx.x * 128;
    int lrow  = lane & 15;
    int khalf = lane >> 4;
    int wm  = (wave & 1) * 64;                         // M half: 2 x 64 rows
    int wn6 = (wave >> 1) * 96;                        // 384-wide N quarter (proj, FF2)
    int wn4 = (wave >> 1) * 64;                        // 256-wide N quarter (FF1)

    // ---- proj staging: A [128][32]sh, B [384][32]sh
    {
        int row = tid >> 2;
        int i0 = (tid & 3) * 16;
        int selem = ((i0 - ((row >> 1) & 3) * 16) & 63) >> 1;
        glds16(attnT + (size_t)(bm + row) * PROJK + selem, As_p + (size_t)tid * 8);
        #pragma unroll
        for (int p = 0; p < 3; ++p) {
            int c = tid + p * 512;
            int rowb = c >> 2;
            int sel2 = (((c & 3) * 16 - ((rowb >> 1) & 3) * 16) & 63) >> 1;
            glds16(WprojT + (size_t)rowb * PROJK + sel2, Bs_p + (size_t)c * 8);
        }
    }
    __syncthreads();

    // ---- proj compute (K=32, one MFMA step), swapped operands
    f32x4 accp[4][6] = {};
    {
        int arot16 = ((lrow >> 1) & 3) * 16;
        int roff = ((khalf * 16 + arot16) & 63) >> 1;
        bf16x8 afp[4], bfp[6];
        #pragma unroll
        for (int i = 0; i < 4; ++i)
            afp[i] = *(const bf16x8*)&As_p[(size_t)(wm + i * 16 + lrow) * 32 + roff];
        #pragma unroll
        for (int i = 0; i < 6; ++i)
            bfp[i] = *(const bf16x8*)&Bs_p[(size_t)(wn6 + i * 16 + lrow) * 32 + roff];
        #pragma unroll
        for (int mi = 0; mi < 4; ++mi)
            #pragma unroll
            for (int ni = 0; ni < 6; ++ni)
                accp[mi][ni] = __builtin_amdgcn_mfma_f32_16x16x32_bf16(bfp[ni], afp[mi], accp[mi][ni], 0, 0, 0);
    }

    // proj epilogue -> x2_lds (fp8 * X2_SCALE, rotated)
    #pragma unroll
    for (int mi = 0; mi < 4; ++mi) {
        int m = wm + mi * 16 + lrow;
        #pragma unroll
        for (int ni = 0; ni < 6; ++ni) {
            int n0 = wn6 + ni * 16 + khalf * 4;
            float4 bv = *(const float4*)(bproj + n0);
            float w[4];
            w[0] = (accp[mi][ni][0] + bv.x) * X2_SCALE;
            w[1] = (accp[mi][ni][1] + bv.y) * X2_SCALE;
            w[2] = (accp[mi][ni][2] + bv.z) * X2_SCALE;
            w[3] = (accp[mi][ni][3] + bv.w) * X2_SCALE;
            *(u32*)&x2_lds[(size_t)(n0 >> 7) * 16384 + (size_t)m * 128 +
                           (((n0 & 127) + (m & 7) * 16) & 127)] = pk4fp8(w);
        }
    }
    __syncthreads();                                   // x2 ready; proj tiles (h1t alias) dead

    int arot8 = (lrow & 7) * 16;
    int off0 = (khalf * 32 + arot8) & 127;
    int off1 = (off0 + 16) & 127;

    f32x4 acc1[4][4] = {};
    f32x4 acc2[4][6] = {};

    for (int nt = 0; nt < 6; ++nt) {
        // ---- FF1: 3 K-steps (K=384), N-chunk 256; W1 frags global->reg; NO barriers
        #pragma unroll
        for (int kk = 0; kk < 3; ++kk) {
            const u8* abase = x2_lds + (size_t)kk * 16384;
            i32x8 a[4];
            #pragma unroll
            for (int i = 0; i < 4; ++i) {
                const u8* rp = abase + (size_t)(wm + i * 16 + lrow) * 128;
                i32x4 lo = *(const i32x4*)(rp + off0);
                i32x4 hi = *(const i32x4*)(rp + off1);
                a[i][0]=lo[0]; a[i][1]=lo[1]; a[i][2]=lo[2]; a[i][3]=lo[3];
                a[i][4]=hi[0]; a[i][5]=hi[1]; a[i][6]=hi[2]; a[i][7]=hi[3];
            }
            const u8* wbase = W1P + ((size_t)((nt * 16 + (wave >> 1) * 4) * 3 + kk)) * 2048
                                  + (size_t)lane * 32;
            i32x8 b[4];
            #pragma unroll
            for (int j = 0; j < 4; ++j) {
                const u8* p = wbase + (size_t)j * 3 * 2048;   // n16+1 advances by 3 fragblocks
                i32x4 lo = *(const i32x4*)p;
                i32x4 hi = *(const i32x4*)(p + 16);
                b[j][0]=lo[0]; b[j][1]=lo[1]; b[j][2]=lo[2]; b[j][3]=lo[3];
                b[j][4]=hi[0]; b[j][5]=hi[1]; b[j][6]=hi[2]; b[j][7]=hi[3];
            }
            #pragma unroll
            for (int mi = 0; mi < 4; ++mi)
                #pragma unroll
                for (int j = 0; j < 4; ++j)
                    acc1[mi][j] = __builtin_amdgcn_mfma_scale_f32_16x16x128_f8f6f4(
                        b[j], a[mi], acc1[mi][j], 0, 0,
                        0, 0x7f7f7f7f, 0, 0x7f7f7f7f);
        }

        // ---- h1 epilogue -> h1t [128][256] (fp8 * H1_SCALE, relu, rotated); zero acc1
        #pragma unroll
        for (int mi = 0; mi < 4; ++mi) {
            int m = wm + mi * 16 + lrow;
            #pragma unroll
            for (int ni = 0; ni < 4; ++ni) {
                int n0 = wn4 + ni * 16 + khalf * 4;
                float4 bv = *(const float4*)(b1 + nt * 256 + n0);
                float w[4];
                w[0] = fmaxf(acc1[mi][ni][0] * FF1_DESCALE + bv.x, 0.f) * H1_SCALE;
                w[1] = fmaxf(acc1[mi][ni][1] * FF1_DESCALE + bv.y, 0.f) * H1_SCALE;
                w[2] = fmaxf(acc1[mi][ni][2] * FF1_DESCALE + bv.z, 0.f) * H1_SCALE;
                w[3] = fmaxf(acc1[mi][ni][3] * FF1_DESCALE + bv.w, 0.f) * H1_SCALE;
                *(u32*)&h1t[(size_t)m * 256 + ((n0 + (m & 7) * 16) & 255)] = pk4fp8(w);
                acc1[mi][ni] = f32x4{0.f, 0.f, 0.f, 0.f};
            }
        }
        __syncthreads();                               // h1t ready (sibling wave-cols wrote our rows)

        // ---- FF2 partial: acc2 += h1t @ W2[k 256-slice nt], 2 sub-k of 128;
        //      W2 frags global->reg, coalesced frag-major (L2-hot)
        #pragma unroll
        for (int sk = 0; sk < 2; ++sk) {
            i32x8 a2[4];
            #pragma unroll
            for (int i = 0; i < 4; ++i) {
                const u8* rp = h1t + (size_t)(wm + i * 16 + lrow) * 256;
                int o0 = (sk * 128 + khalf * 32 + arot8) & 255;
                int o1 = (sk * 128 + khalf * 32 + 16 + arot8) & 255;
                i32x4 lo = *(const i32x4*)(rp + o0);
                i32x4 hi = *(const i32x4*)(rp + o1);
                a2[i][0]=lo[0]; a2[i][1]=lo[1]; a2[i][2]=lo[2]; a2[i][3]=lo[3];
                a2[i][4]=hi[0]; a2[i][5]=hi[1]; a2[i][6]=hi[2]; a2[i][7]=hi[3];
            }
            int kc = nt * 2 + sk;
            #pragma unroll
            for (int half = 0; half < 2; ++half) {
                i32x8 bw[3];
                #pragma unroll
                for (int j = 0; j < 3; ++j) {
                    int n16 = (wave >> 1) * 6 + half * 3 + j;
                    const u8* p = W2P + ((size_t)n16 * 12 + kc) * 2048 + (size_t)lane * 32;
                    i32x4 lo = *(const i32x4*)p;
                    i32x4 hi = *(const i32x4*)(p + 16);
                    bw[j][0]=lo[0]; bw[j][1]=lo[1]; bw[j][2]=lo[2]; bw[j][3]=lo[3];
                    bw[j][4]=hi[0]; bw[j][5]=hi[1]; bw[j][6]=hi[2]; bw[j][7]=hi[3];
                }
                #pragma unroll
                for (int mi = 0; mi < 4; ++mi)
                    #pragma unroll
                    for (int j = 0; j < 3; ++j)
                        acc2[mi][half * 3 + j] = __builtin_amdgcn_mfma_scale_f32_16x16x128_f8f6f4(
                            bw[j], a2[mi], acc2[mi][half * 3 + j], 0, 0,
                            0, 0x7f7f7f7f, 0, 0x7f7f7f7f);
            }
        }
        __syncthreads();                               // h1t reads done before next nt write
    }

    // ---- x3 epilogue: bf16 via rotated LDS [128 rows][3 chunks][256B], coalesced stores
    u8* Ep = smem;                                     // 96KB overlay (x2/h1t dead)
    #pragma unroll
    for (int mi = 0; mi < 4; ++mi) {
        int m = wm + mi * 16 + lrow;
        #pragma unroll
        for (int ni = 0; ni < 6; ++ni) {
            int n0 = wn6 + ni * 16 + khalf * 4;
            float4 bv = *(const float4*)(b2 + n0);
            union { short s[4]; uint2 u; } pk;
            pk.s[0] = f2s(acc2[mi][ni][0] * FF2_DESCALE + bv.x);
            pk.s[1] = f2s(acc2[mi][ni][1] * FF2_DESCALE + bv.y);
            pk.s[2] = f2s(acc2[mi][ni][2] * FF2_DESCALE + bv.z);
            pk.s[3] = f2s(acc2[mi][ni][3] * FF2_DESCALE + bv.w);
            *(uint2*)&Ep[(size_t)m * 768 + ((n0 >> 7) << 8) +
                         ((((n0 & 127) * 2) + (m & 7) * 16) & 255)] = pk.u;
        }
    }
    __syncthreads();
    #pragma unroll
    for (int p = 0; p < 12; ++p) {
        int c = tid + p * 512;
        int row = c / 48;
        int sl = c - row * 48;
        int g0 = sl * 16;
        int chunk = g0 >> 8;
        int loc = g0 & 255;
        uint4 v = *(const uint4*)&Ep[(size_t)row * 768 + (chunk << 8) +
                                     ((loc + (row & 7) * 16) & 255)];
        *(uint4*)((u8*)x3 + (size_t)(bm + row) * 768 + g0) = v;
    }
}

// ---------------- LM head + fused CE loss + grid-level loss finish (atomics)
__global__ __launch_bounds__(512)
void lm_loss_kernel(const bf16* __restrict__ A, const bf16* __restrict__ Bt,
                    const float* __restrict__ bias, const int* __restrict__ targets,
                    float* __restrict__ outf, float* __restrict__ lossbuf,
                    float* __restrict__ out_loss, int M, int K) {
    __shared__ short As[128][32];
    __shared__ short Bs[128][32];
    __shared__ float Ls[128][66];
    __shared__ float red[128];
    int tid  = threadIdx.x;
    int lane = tid & 63;
    int wave = tid >> 6;
    int bm = blockIdx.x * 128;
    int wm = (wave & 1) * 64;
    int wn = (wave >> 1) * 32;
    int lrow  = lane & 15;
    int khalf = lane >> 4;

    int row = tid >> 2;
    int i0 = (tid & 3) * 16;
    int selem = ((i0 - ((row >> 1) & 3) * 16) & 63) >> 1;
    int arot = ((lrow >> 1) & 3) * 16;
    int roff = ((khalf * 16 + arot) & 63) >> 1;

    f32x4 acc[4][2] = {};
    for (int k0 = 0; k0 < K; k0 += 32) {
        glds16(A  + (size_t)(bm + row) * K + k0 + selem, (short*)As + (size_t)tid * 8);
        glds16(Bt + (size_t)row * K + k0 + selem,        (short*)Bs + (size_t)tid * 8);
        __syncthreads();

        bf16x8 af[4], bff[2];
        #pragma unroll
        for (int i = 0; i < 4; ++i)
            af[i] = *(const bf16x8*)&As[wm + i * 16 + lrow][roff];
        #pragma unroll
        for (int i = 0; i < 2; ++i)
            bff[i] = *(const bf16x8*)&Bs[wn + i * 16 + lrow][roff];
        #pragma unroll
        for (int mi = 0; mi < 4; ++mi)
            #pragma unroll
            for (int ni = 0; ni < 2; ++ni)
                acc[mi][ni] = __builtin_amdgcn_mfma_f32_16x16x32_bf16(af[mi], bff[ni], acc[mi][ni], 0, 0, 0);
        __syncthreads();
    }

    #pragma unroll
    for (int ni = 0; ni < 2; ++ni) {
        int col = wn + ni * 16 + lrow;
        if (col >= VOC) continue;
        float bv = bias[col];
        #pragma unroll
        for (int mi = 0; mi < 4; ++mi) {
            int lr = wm + mi * 16 + khalf * 4;
            #pragma unroll
            for (int r = 0; r < 4; ++r) {
                float v = acc[mi][ni][r] + bv;
                outf[(size_t)(bm + lr + r) * VOC + col] = v;
                Ls[lr + r][col] = v;
            }
        }
    }
    __syncthreads();

    if (tid < 128) {
        int token = bm + tid;
        int tgt = targets[token];
        float m = -1e30f, s = 0.f;
        #pragma unroll 8
        for (int c = 0; c < VOC; ++c) {
            float v = Ls[tid][c];
            float mn = fmaxf(m, v);
            s = s * __expf(m - mn) + __expf(v - mn);
            m = mn;
        }
        red[tid] = m + logf(s) - Ls[tid][tgt];
    }
    __syncthreads();
    if (tid < 64) {
        float s = red[tid] + red[tid + 64];
        #pragma unroll
        for (int off = 32; off > 0; off >>= 1) s += __shfl_xor(s, off);
        if (tid == 0) {
            atomicAdd(&lossbuf[0], s);
            __threadfence();
            int done = atomicAdd(&((int*)lossbuf)[1], 1);
            if (done == (NTOK / 128) - 1) {     // last block
                __threadfence();
                float total = atomicAdd(&lossbuf[0], 0.0f);
                out_loss[0] = total / (float)NTOK;
            }
        }
    }
}

extern "C" void kernel_launch(void* const* d_in, const int* in_sizes, int n_in,
                              void* d_out, int out_size, void* d_ws, size_t ws_size,
                              hipStream_t stream) {
    const int*   idx     = (const int*)  d_in[0];
    const int*   targets = (const int*)  d_in[1];
    const float* tok_emb = (const float*)d_in[2];
    const float* pos_emb = (const float*)d_in[3];
    const float* Wq      = (const float*)d_in[4];
    const float* Wk      = (const float*)d_in[5];
    const float* Wv      = (const float*)d_in[6];
    const float* Wproj   = (const float*)d_in[7];
    const float* bproj   = (const float*)d_in[8];
    const float* W1      = (const float*)d_in[9];
    const float* b1      = (const float*)d_in[10];
    const float* W2      = (const float*)d_in[11];
    const float* b2      = (const float*)d_in[12];
    const float* Wlm     = (const float*)d_in[13];
    const float* blm     = (const float*)d_in[14];

    char* ws = (char*)d_ws;
    bf16*  WprojT = (bf16*) (ws + 0);                       // 24576 B
    float* qkvbuf = (float*)(ws + 25165824);                // 9437184 B
    bf16*  attnT  = (bf16*) (ws + 34603008);                // 2097152 B
    bf16*  xtab   = (bf16*) (ws + 37748736);                // 12779520 B
    bf16*  x3     = (bf16*) (ws + 163577856);               // 25165824 B
    float* lossbuf= (float*)(ws + 188743680);               // [0]=sum, [1]=counter
    u8*    W1P    = (u8*)   (ws + 188874752);               // 589824 B (frag-major)
    u8*    W2P    = (u8*)   (ws + 190054400);               // 589824 B (frag-major)
    bf16*  WqkvT  = (bf16*) (ws + 191234048);               // 98304 B
    bf16*  WlmT   = (bf16*) (ws + 191332352);               // 98304 B

    float* out_logits = (float*)d_out;                      // [32768*65] f32
    float* out_loss   = out_logits + (size_t)NTOK * VOC;    // [1]

    pack_all_kernel<<<640 + 576 + XROWS / 4, 256, 0, stream>>>(
        Wq, Wk, Wv, Wlm, Wproj, W1, W2, tok_emb, pos_emb,
        WqkvT, WlmT, WprojT, W1P, W2P, xtab, lossbuf);

    qkv_gather_kernel<<<NTOK / 128, 512, 0, stream>>>(idx, xtab, WqkvT, qkvbuf);
    attn_kernel<<<NB * NH, T_SEQ, 0, stream>>>(qkvbuf, attnT);

    // proj + FF1 + FF2 fused: attnT -> x3 (x2, h1 stay in LDS; W1/W2 stream from L2)
    ff_mega_kernel<<<NTOK / 128, 512, 0, stream>>>(attnT, WprojT, bproj,
                                                   W1P, b1, W2P, b2, x3);

    // LM head + fused loss + grid loss finish
    lm_loss_kernel<<<NTOK / 128, 512, 0, stream>>>(x3, WlmT, blm, targets,
                                                   out_logits, lossbuf, out_loss, NTOK, C_EMB);
}